// Round 2
// baseline (685.832 us; speedup 1.0000x reference)
//
#include <hip/hip_runtime.h>
#include <math.h>

#define BB  16
#define IDF 128
#define CDF 256
#define SL  48
#define QQ  16384   // 128*128

// ws layout (floats): srcT [B][IDF][SL] | sent [B][IDF] | wsvT [IDF][IDF] (i-major)
#define WS_SRCT 0
#define WS_SENT (BB*IDF*SL)
#define WS_WSVT (WS_SENT + BB*IDF)

__global__ __launch_bounds__(256) void prep_kernel(
    const float* __restrict__ context,   // [B][CDF][SL]
    const float* __restrict__ w_ctx,     // [IDF][CDF]
    const float* __restrict__ sentence,  // [B][100]
    const float* __restrict__ w_lin,     // [IDF][100]
    const float* __restrict__ b_lin,     // [IDF]
    const float* __restrict__ w_sv,      // [IDF][IDF] (o,i)
    float* __restrict__ srcT,            // [B][IDF][SL]
    float* __restrict__ sent,            // [B][IDF]
    float* __restrict__ wsvT)            // [IDF][IDF] (i,o)
{
    const int b    = blockIdx.x;
    const int iblk = blockIdx.y;       // 0..3, 32 output rows each
    const int t    = threadIdx.x;

    __shared__ float ctx_lds[CDF * SL];   // 48 KB
    __shared__ float w_lds[32 * CDF];     // 32 KB

    // stage context[b] (12288 floats) via float4
    {
        const float4* g4 = (const float4*)(context + b * CDF * SL);
        float4* s4 = (float4*)ctx_lds;
        #pragma unroll
        for (int r = 0; r < (CDF * SL) / 1024; ++r)   // 3072 float4 / 256
            s4[r * 256 + t] = g4[r * 256 + t];
    }
    // stage 32 rows of w_ctx via float4
    const int i0 = iblk * 32;
    {
        const float4* g4 = (const float4*)(w_ctx + i0 * CDF);
        float4* s4 = (float4*)w_lds;
        #pragma unroll
        for (int r = 0; r < (32 * CDF) / 1024; ++r)
            s4[r * 256 + t] = g4[r * 256 + t];
    }
    __syncthreads();

    // srcT[b][i0+ii][s] = sum_c w_ctx[i0+ii][c] * context[b][c][s]
    for (int r = 0; r < 6; ++r) {
        int idx = r * 256 + t;          // 0..1535
        int ii = idx / SL, s = idx % SL;
        float a0 = 0.f, a1 = 0.f, a2 = 0.f, a3 = 0.f;
        for (int c = 0; c < CDF; c += 4) {
            a0 += w_lds[ii * CDF + c + 0] * ctx_lds[(c + 0) * SL + s];
            a1 += w_lds[ii * CDF + c + 1] * ctx_lds[(c + 1) * SL + s];
            a2 += w_lds[ii * CDF + c + 2] * ctx_lds[(c + 2) * SL + s];
            a3 += w_lds[ii * CDF + c + 3] * ctx_lds[(c + 3) * SL + s];
        }
        srcT[(b * IDF + i0 + ii) * SL + s] = (a0 + a1) + (a2 + a3);
    }

    // sent[b][o] = b_lin[o] + sentence[b]·w_lin[o]
    if (t < 32) {
        int o = iblk * 32 + t;
        float a = b_lin[o];
        for (int k = 0; k < 100; ++k)
            a += sentence[b * 100 + k] * w_lin[o * 100 + k];
        sent[b * IDF + o] = a;
    }

    // wsvT[i][o] = w_sv[o][i]  (only b==0 blocks)
    if (b == 0) {
        for (int r = 0; r < 16; ++r) {
            int idx = iblk * 4096 + r * 256 + t;
            int i = idx >> 7, o = idx & 127;
            wsvT[idx] = w_sv[o * IDF + i];
        }
    }
}

// Word-attention path: logits -> mask -> softmax -> word_attn + weightedContext
// Each thread owns 2 consecutive q. srcT rows live in LDS (broadcast reads).
__global__ __launch_bounds__(256) void attn_kernel(
    const float* __restrict__ input,  // [B][IDF][Q]
    const float* __restrict__ srcT,   // [B][IDF][SL]
    const int*   __restrict__ mask,   // [B][SL]
    float* __restrict__ wctx,         // out0 [B][IDF][Q]
    float* __restrict__ wattn)        // out2 [B][SL][Q]
{
    const int bid = blockIdx.x;        // 512 blocks: b = bid>>5
    const int b   = bid >> 5;
    const int q0  = (bid & 31) * 512;
    const int t   = threadIdx.x;
    const int q   = q0 + t * 2;

    __shared__ float sT[IDF * SL];     // 24 KB, [i][s]
    __shared__ float sbias[SL];

    // stage srcT[b] via float4 (1536 float4)
    {
        const float4* g4 = (const float4*)(srcT + b * IDF * SL);
        float4* s4 = (float4*)sT;
        #pragma unroll
        for (int r = 0; r < 6; ++r) s4[r * 256 + t] = g4[r * 256 + t];
    }
    if (t < SL) sbias[t] = mask[b * SL + t] ? -INFINITY : 0.f;
    __syncthreads();

    float a0[SL], a1[SL];
    #pragma unroll
    for (int s = 0; s < SL; ++s) { a0[s] = 0.f; a1[s] = 0.f; }

    const float* inp = input + (size_t)b * IDF * QQ + q;

    // phase 1: logits  a[s] += input[i][q] * srcT[i][s]
    for (int i = 0; i < IDF; ++i) {
        float2 v = *(const float2*)(inp + (size_t)i * QQ);
        const float4* row4 = (const float4*)(sT + i * SL);
        #pragma unroll
        for (int j = 0; j < 12; ++j) {
            float4 r4 = row4[j];
            a0[j*4+0] += v.x * r4.x;  a1[j*4+0] += v.y * r4.x;
            a0[j*4+1] += v.x * r4.y;  a1[j*4+1] += v.y * r4.y;
            a0[j*4+2] += v.x * r4.z;  a1[j*4+2] += v.y * r4.z;
            a0[j*4+3] += v.x * r4.w;  a1[j*4+3] += v.y * r4.w;
        }
    }

    // mask bias + softmax over s (per q)
    float m0 = -INFINITY, m1 = -INFINITY;
    #pragma unroll
    for (int s = 0; s < SL; ++s) {
        float bv = sbias[s];
        a0[s] += bv; a1[s] += bv;
        m0 = fmaxf(m0, a0[s]); m1 = fmaxf(m1, a1[s]);
    }
    float sum0 = 0.f, sum1 = 0.f;
    #pragma unroll
    for (int s = 0; s < SL; ++s) {
        a0[s] = __expf(a0[s] - m0); sum0 += a0[s];
        a1[s] = __expf(a1[s] - m1); sum1 += a1[s];
    }
    float inv0 = 1.f / sum0, inv1 = 1.f / sum1;
    #pragma unroll
    for (int s = 0; s < SL; ++s) {
        a0[s] *= inv0; a1[s] *= inv1;
        float2 p; p.x = a0[s]; p.y = a1[s];
        *(float2*)(wattn + ((size_t)b * SL + s) * QQ + q) = p;
    }

    // phase 3: wctx[i][q] = sum_s srcT[i][s] * attn[q][s]
    for (int i = 0; i < IDF; ++i) {
        const float4* row4 = (const float4*)(sT + i * SL);
        float x0 = 0.f, x1 = 0.f, x2 = 0.f, x3 = 0.f;
        float y0 = 0.f, y1 = 0.f, y2 = 0.f, y3 = 0.f;
        #pragma unroll
        for (int j = 0; j < 12; ++j) {
            float4 r4 = row4[j];
            x0 += r4.x * a0[j*4+0];  y0 += r4.x * a1[j*4+0];
            x1 += r4.y * a0[j*4+1];  y1 += r4.y * a1[j*4+1];
            x2 += r4.z * a0[j*4+2];  y2 += r4.z * a1[j*4+2];
            x3 += r4.w * a0[j*4+3];  y3 += r4.w * a1[j*4+3];
        }
        float2 w; w.x = (x0 + x1) + (x2 + x3); w.y = (y0 + y1) + (y2 + y3);
        *(float2*)(wctx + ((size_t)b * IDF + i) * QQ + q) = w;
    }
}

// Sentence path: sv = w_sv @ (input*sent), softmax over channels, outputs
__global__ __launch_bounds__(256) void sent_kernel(
    const float* __restrict__ input,  // [B][IDF][Q]
    const float* __restrict__ wsvT,   // [IDF(i)][IDF(o)]
    const float* __restrict__ sent,   // [B][IDF]
    float* __restrict__ wsent,        // out1 [B][IDF][Q]
    float* __restrict__ satt)         // out3 [B][IDF][Q]
{
    const int b  = blockIdx.x;
    const int q0 = blockIdx.y * 64;
    const int t  = threadIdx.x;

    __shared__ float xs[IDF * 64];     // 32 KB, [i][q]
    __shared__ float red[2][4][64];

    // stage x[i][q] = input[b,i,q0+q] * sent[b,i]  via float4
    {
        float4* s4 = (float4*)xs;
        #pragma unroll
        for (int r = 0; r < 8; ++r) {
            int idx = r * 256 + t;            // float4 index, 0..2047
            int i = idx >> 4, q4 = idx & 15;
            const float4* g4 =
                (const float4*)(input + ((size_t)b * IDF + i) * QQ + q0);
            float4 v = g4[q4];
            float sc = sent[b * IDF + i];
            v.x *= sc; v.y *= sc; v.z *= sc; v.w *= sc;
            s4[idx] = v;
        }
    }
    __syncthreads();

    const int wave = t >> 6;           // 0..3
    const int lane = t & 63;

    float acc[32];
    #pragma unroll
    for (int oo = 0; oo < 32; ++oo) acc[oo] = 0.f;

    // acc[oo] = sum_i wsvT[i][wave*32+oo] * x[i][lane]
    const float* wT = wsvT + wave * 32;   // wave-uniform -> scalar loads
    for (int i = 0; i < IDF; ++i) {
        float v = xs[i * 64 + lane];
        #pragma unroll
        for (int oo = 0; oo < 32; ++oo)
            acc[oo] += wT[i * IDF + oo] * v;
    }

    // softmax over the 128 channels (32 per wave x 4 waves)
    float lmax = -INFINITY;
    #pragma unroll
    for (int oo = 0; oo < 32; ++oo) lmax = fmaxf(lmax, acc[oo]);
    red[0][wave][lane] = lmax;
    __syncthreads();
    float m = fmaxf(fmaxf(red[0][0][lane], red[0][1][lane]),
                    fmaxf(red[0][2][lane], red[0][3][lane]));
    float lsum = 0.f;
    #pragma unroll
    for (int oo = 0; oo < 32; ++oo) { acc[oo] = __expf(acc[oo] - m); lsum += acc[oo]; }
    red[1][wave][lane] = lsum;
    __syncthreads();
    float tot = red[1][0][lane] + red[1][1][lane] + red[1][2][lane] + red[1][3][lane];
    float inv = 1.f / tot;

    #pragma unroll
    for (int oo = 0; oo < 32; ++oo) {
        int o = wave * 32 + oo;
        float p = acc[oo] * inv;
        size_t off = ((size_t)b * IDF + o) * QQ + q0 + lane;
        satt[off]  = p;
        wsent[off] = sent[b * IDF + o] * p;
    }
}

extern "C" void kernel_launch(void* const* d_in, const int* in_sizes, int n_in,
                              void* d_out, int out_size, void* d_ws, size_t ws_size,
                              hipStream_t stream) {
    const float* input    = (const float*)d_in[0];
    const float* sentence = (const float*)d_in[1];
    const float* context  = (const float*)d_in[2];
    const int*   mask     = (const int*)d_in[3];
    const float* w_ctx    = (const float*)d_in[4];
    const float* w_sv     = (const float*)d_in[5];
    const float* w_lin    = (const float*)d_in[6];
    const float* b_lin    = (const float*)d_in[7];

    float* out = (float*)d_out;
    float* out_wctx  = out;                                   // [B][IDF][Q]
    float* out_wsent = out + (size_t)BB * IDF * QQ;           // [B][IDF][Q]
    float* out_wattn = out + 2 * (size_t)BB * IDF * QQ;       // [B][SL][Q]
    float* out_satt  = out_wattn + (size_t)BB * SL * QQ;      // [B][IDF][Q]

    float* ws   = (float*)d_ws;
    float* srcT = ws + WS_SRCT;
    float* sent = ws + WS_SENT;
    float* wsvT = ws + WS_WSVT;

    prep_kernel<<<dim3(16, 4), 256, 0, stream>>>(context, w_ctx, sentence,
                                                 w_lin, b_lin, w_sv,
                                                 srcT, sent, wsvT);
    attn_kernel<<<dim3(512), 256, 0, stream>>>(input, srcT, mask,
                                               out_wctx, out_wattn);
    sent_kernel<<<dim3(16, 256), 256, 0, stream>>>(input, wsvT, sent,
                                                   out_wsent, out_satt);
}

// Round 3
// 336.622 us; speedup vs baseline: 2.0374x; 2.0374x over previous
//
#include <hip/hip_runtime.h>
#include <math.h>

#define BB  16
#define IDF 128
#define CDF 256
#define SL  48
#define QQ  16384   // 128*128

// ws layout (floats): srcT [B][IDF][SL] | sent [B][IDF] | wsvT [IDF][IDF] (i-major)
#define WS_SRCT 0
#define WS_SENT (BB*IDF*SL)
#define WS_WSVT (WS_SENT + BB*IDF)

__global__ __launch_bounds__(256) void prep_kernel(
    const float* __restrict__ context,   // [B][CDF][SL]
    const float* __restrict__ w_ctx,     // [IDF][CDF]
    const float* __restrict__ sentence,  // [B][100]
    const float* __restrict__ w_lin,     // [IDF][100]
    const float* __restrict__ b_lin,     // [IDF]
    const float* __restrict__ w_sv,      // [IDF][IDF] (o,i)
    float* __restrict__ srcT,            // [B][IDF][SL]
    float* __restrict__ sent,            // [B][IDF]
    float* __restrict__ wsvT)            // [IDF][IDF] (i,o)
{
    const int b    = blockIdx.x;
    const int iblk = blockIdx.y;       // 0..3, 32 output rows each
    const int t    = threadIdx.x;

    __shared__ float ctx_lds[CDF * SL];   // 48 KB
    __shared__ float w_lds[32 * CDF];     // 32 KB

    // stage context[b] (12288 floats) via float4
    {
        const float4* g4 = (const float4*)(context + b * CDF * SL);
        float4* s4 = (float4*)ctx_lds;
        #pragma unroll
        for (int r = 0; r < (CDF * SL) / 1024; ++r)   // 3072 float4 / 256
            s4[r * 256 + t] = g4[r * 256 + t];
    }
    // stage 32 rows of w_ctx via float4
    const int i0 = iblk * 32;
    {
        const float4* g4 = (const float4*)(w_ctx + i0 * CDF);
        float4* s4 = (float4*)w_lds;
        #pragma unroll
        for (int r = 0; r < (32 * CDF) / 1024; ++r)
            s4[r * 256 + t] = g4[r * 256 + t];
    }
    __syncthreads();

    // srcT[b][i0+ii][s] = sum_c w_ctx[i0+ii][c] * context[b][c][s]
    for (int r = 0; r < 6; ++r) {
        int idx = r * 256 + t;          // 0..1535
        int ii = idx / SL, s = idx % SL;
        float a0 = 0.f, a1 = 0.f, a2 = 0.f, a3 = 0.f;
        for (int c = 0; c < CDF; c += 4) {
            a0 += w_lds[ii * CDF + c + 0] * ctx_lds[(c + 0) * SL + s];
            a1 += w_lds[ii * CDF + c + 1] * ctx_lds[(c + 1) * SL + s];
            a2 += w_lds[ii * CDF + c + 2] * ctx_lds[(c + 2) * SL + s];
            a3 += w_lds[ii * CDF + c + 3] * ctx_lds[(c + 3) * SL + s];
        }
        srcT[(b * IDF + i0 + ii) * SL + s] = (a0 + a1) + (a2 + a3);
    }

    // sent[b][o] = b_lin[o] + sentence[b]·w_lin[o]
    if (t < 32) {
        int o = iblk * 32 + t;
        float a = b_lin[o];
        for (int k = 0; k < 100; ++k)
            a += sentence[b * 100 + k] * w_lin[o * 100 + k];
        sent[b * IDF + o] = a;
    }

    // wsvT[i][o] = w_sv[o][i]  (only b==0 blocks)
    if (b == 0) {
        for (int r = 0; r < 16; ++r) {
            int idx = iblk * 4096 + r * 256 + t;
            int i = idx >> 7, o = idx & 127;
            wsvT[idx] = w_sv[o * IDF + i];
        }
    }
}

// Word-attention path: logits -> mask -> softmax -> word_attn + weightedContext
// 1 q per thread; 1024 blocks -> 4 blocks/CU for latency hiding.
__global__ __launch_bounds__(256) void attn_kernel(
    const float* __restrict__ input,  // [B][IDF][Q]
    const float* __restrict__ srcT,   // [B][IDF][SL]
    const int*   __restrict__ mask,   // [B][SL]
    float* __restrict__ wctx,         // out0 [B][IDF][Q]
    float* __restrict__ wattn)        // out2 [B][SL][Q]
{
    const int bid = blockIdx.x;        // 1024 blocks
    const int b   = bid >> 6;
    const int q   = (bid & 63) * 256 + threadIdx.x;
    const int t   = threadIdx.x;

    __shared__ float sT[IDF * SL];     // 24 KB, [i][s]
    __shared__ float sbias[SL];

    // stage srcT[b] via float4 (1536 float4)
    {
        const float4* g4 = (const float4*)(srcT + b * IDF * SL);
        float4* s4 = (float4*)sT;
        #pragma unroll
        for (int r = 0; r < 6; ++r) s4[r * 256 + t] = g4[r * 256 + t];
    }
    if (t < SL) sbias[t] = mask[b * SL + t] ? -INFINITY : 0.f;
    __syncthreads();

    float a0[SL];
    #pragma unroll
    for (int s = 0; s < SL; ++s) a0[s] = 0.f;

    const float* inp = input + (size_t)b * IDF * QQ + q;

    // phase 1: logits  a[s] += input[i][q] * srcT[i][s]
    #pragma unroll 2
    for (int i = 0; i < IDF; ++i) {
        float v = inp[(size_t)i * QQ];
        const float4* row4 = (const float4*)(sT + i * SL);
        #pragma unroll
        for (int j = 0; j < 12; ++j) {
            float4 r4 = row4[j];
            a0[j*4+0] += v * r4.x;
            a0[j*4+1] += v * r4.y;
            a0[j*4+2] += v * r4.z;
            a0[j*4+3] += v * r4.w;
        }
    }

    // mask bias + softmax over s
    float m0 = -INFINITY;
    #pragma unroll
    for (int s = 0; s < SL; ++s) {
        a0[s] += sbias[s];
        m0 = fmaxf(m0, a0[s]);
    }
    float sum0 = 0.f;
    #pragma unroll
    for (int s = 0; s < SL; ++s) { a0[s] = __expf(a0[s] - m0); sum0 += a0[s]; }
    float inv0 = 1.f / sum0;
    #pragma unroll
    for (int s = 0; s < SL; ++s) {
        a0[s] *= inv0;
        wattn[((size_t)b * SL + s) * QQ + q] = a0[s];
    }

    // phase 3: wctx[i][q] = sum_s srcT[i][s] * attn[q][s]
    #pragma unroll 2
    for (int i = 0; i < IDF; ++i) {
        const float4* row4 = (const float4*)(sT + i * SL);
        float x0 = 0.f, x1 = 0.f, x2 = 0.f, x3 = 0.f;
        #pragma unroll
        for (int j = 0; j < 12; ++j) {
            float4 r4 = row4[j];
            x0 += r4.x * a0[j*4+0];
            x1 += r4.y * a0[j*4+1];
            x2 += r4.z * a0[j*4+2];
            x3 += r4.w * a0[j*4+3];
        }
        wctx[((size_t)b * IDF + i) * QQ + q] = (x0 + x1) + (x2 + x3);
    }
}

// Sentence path: sv = w_sv @ (input*sent), softmax over channels, outputs
__global__ __launch_bounds__(256) void sent_kernel(
    const float* __restrict__ input,  // [B][IDF][Q]
    const float* __restrict__ wsvT,   // [IDF(i)][IDF(o)]
    const float* __restrict__ sent,   // [B][IDF]
    float* __restrict__ wsent,        // out1 [B][IDF][Q]
    float* __restrict__ satt)         // out3 [B][IDF][Q]
{
    const int b  = blockIdx.x;
    const int q0 = blockIdx.y * 64;
    const int t  = threadIdx.x;

    __shared__ float xs[IDF * 64];     // 32 KB, [i][q]
    __shared__ float red[2][4][64];

    // stage x[i][q] = input[b,i,q0+q] * sent[b,i]  via float4
    {
        float4* s4 = (float4*)xs;
        #pragma unroll
        for (int r = 0; r < 8; ++r) {
            int idx = r * 256 + t;            // float4 index, 0..2047
            int i = idx >> 4, q4 = idx & 15;
            const float4* g4 =
                (const float4*)(input + ((size_t)b * IDF + i) * QQ + q0);
            float4 v = g4[q4];
            float sc = sent[b * IDF + i];
            v.x *= sc; v.y *= sc; v.z *= sc; v.w *= sc;
            s4[idx] = v;
        }
    }
    __syncthreads();

    // readfirstlane: REQUIRED so the compiler proves wT wave-uniform and
    // scalarizes the weight loads (dropping it cost 3.5x in round 2: the
    // per-lane fallback pushed 17 GB through L2 at the 32 TB/s ceiling).
    const int wave = __builtin_amdgcn_readfirstlane(t >> 6);  // 0..3
    const int lane = t & 63;

    float acc[32];
    #pragma unroll
    for (int oo = 0; oo < 32; ++oo) acc[oo] = 0.f;

    // acc[oo] = sum_i wsvT[i][wave*32+oo] * x[i][lane]
    const float* wT = wsvT + wave * 32;   // wave-uniform -> scalar loads
    for (int i = 0; i < IDF; ++i) {
        float v = xs[i * 64 + lane];
        #pragma unroll
        for (int oo = 0; oo < 32; ++oo)
            acc[oo] += wT[i * IDF + oo] * v;
    }

    // softmax over the 128 channels (32 per wave x 4 waves)
    float lmax = -INFINITY;
    #pragma unroll
    for (int oo = 0; oo < 32; ++oo) lmax = fmaxf(lmax, acc[oo]);
    red[0][wave][lane] = lmax;
    __syncthreads();
    float m = fmaxf(fmaxf(red[0][0][lane], red[0][1][lane]),
                    fmaxf(red[0][2][lane], red[0][3][lane]));
    float lsum = 0.f;
    #pragma unroll
    for (int oo = 0; oo < 32; ++oo) { acc[oo] = __expf(acc[oo] - m); lsum += acc[oo]; }
    red[1][wave][lane] = lsum;
    __syncthreads();
    float tot = red[1][0][lane] + red[1][1][lane] + red[1][2][lane] + red[1][3][lane];
    float inv = 1.f / tot;

    #pragma unroll
    for (int oo = 0; oo < 32; ++oo) {
        int o = wave * 32 + oo;
        float p = acc[oo] * inv;
        size_t off = ((size_t)b * IDF + o) * QQ + q0 + lane;
        satt[off]  = p;
        wsent[off] = sent[b * IDF + o] * p;
    }
}

extern "C" void kernel_launch(void* const* d_in, const int* in_sizes, int n_in,
                              void* d_out, int out_size, void* d_ws, size_t ws_size,
                              hipStream_t stream) {
    const float* input    = (const float*)d_in[0];
    const float* sentence = (const float*)d_in[1];
    const float* context  = (const float*)d_in[2];
    const int*   mask     = (const int*)d_in[3];
    const float* w_ctx    = (const float*)d_in[4];
    const float* w_sv     = (const float*)d_in[5];
    const float* w_lin    = (const float*)d_in[6];
    const float* b_lin    = (const float*)d_in[7];

    float* out = (float*)d_out;
    float* out_wctx  = out;                                   // [B][IDF][Q]
    float* out_wsent = out + (size_t)BB * IDF * QQ;           // [B][IDF][Q]
    float* out_wattn = out + 2 * (size_t)BB * IDF * QQ;       // [B][SL][Q]
    float* out_satt  = out_wattn + (size_t)BB * SL * QQ;      // [B][IDF][Q]

    float* ws   = (float*)d_ws;
    float* srcT = ws + WS_SRCT;
    float* sent = ws + WS_SENT;
    float* wsvT = ws + WS_WSVT;

    prep_kernel<<<dim3(16, 4), 256, 0, stream>>>(context, w_ctx, sentence,
                                                 w_lin, b_lin, w_sv,
                                                 srcT, sent, wsvT);
    attn_kernel<<<dim3(1024), 256, 0, stream>>>(input, srcT, mask,
                                                out_wctx, out_wattn);
    sent_kernel<<<dim3(16, 256), 256, 0, stream>>>(input, wsvT, sent,
                                                   out_wsent, out_satt);
}